// Round 1
// 101.500 us; speedup vs baseline: 1.0272x; 1.0272x over previous
//
#include <hip/hip_runtime.h>
#include <math.h>

// Problem constants (fixed by reference)
#define NB 8
#define NM 16
#define NC 3
#define NH 128
#define NW 128
#define NG (NH * NW)            // 16384 spatial elems per image
#define NGF (NH * (NW / 2 + 1)) // 8320 rfft2 elems per image
#define NKH 32                  // kept freq rows  (int(128*0.25))
#define NKW 16                  // kept freq cols  (int(65*0.25))
#define NK (NKH * NKW)          // 512 kept coefficients
#define N_PRED_IMG (NB * NM * NC)    // 384 pred images
#define N_IMG (N_PRED_IMG + NB * NC) // 408 images incl. target

#define PT_BLOCKS 384   // point-CRPS blocks (4 cols/thread)
#define FQ_BLOCKS 48    // freq-CRPS blocks

// ws layout:
//  [0,    6144) : double2 pp[384]   point partials {s_mae, s_pair}
//  [6144, 6912) : double2 fp[48]    freq partials
//  [6912, 6916) : unsigned ctr      last-block-done counter
//  [7168, +835584) : float mag[408*512]
#define WS_PP_OFF  0
#define WS_FP_OFF  6144
#define WS_CTR_OFF 6912
#define WS_MAG_OFF 7168

#define PI_F 3.14159265358979323846f

__device__ __forceinline__ float2 cmul(float2 a, float2 b) {
  return make_float2(a.x * b.x - a.y * b.y, a.x * b.y + a.y * b.x);
}

// ---------------------------------------------------------------------------
// Kernel 1: fused pointwise-CRPS (blocks [0,384)) + per-image DFT+|.|
// (blocks [384,792), one image each).
//
// DFT restructure vs previous version:
//  - Row stage reads rows DIRECTLY from global. Lanes 0..15 of a wave share
//    each address (16-way broadcast, free in the coalescer); rows are 512 B
//    contiguous so the w4 walk is line-sequential. This removes the xs4 LDS
//    staging and 8 of the 9 __syncthreads per block.
//  - One twiddle recurrence per thread for the WHOLE row stage (128 steps),
//    amortized over 8 rows (thread = (kw = t&15, rg = t>>4), rows rg+16j).
//    Per w-step: 16 fma + 4 twiddle ops = 2.5 VALU ops/row (was 4).
//  - Column stage unchanged: thread = (kh = t>>3, kw pair), float4 LDS reads,
//    conflict-free.
__global__ __launch_bounds__(256) void fused_main_kernel(
    const float* __restrict__ pred,   // (B,M,C,128,128) flat
    const float* __restrict__ tgt,    // (B,C,128,128) flat
    double2* __restrict__ pp,         // [PT_BLOCKS]
    float* __restrict__ mag,          // [408*512]
    unsigned* __restrict__ ctr) {
  __shared__ float2 Yl[NH * NKW];     // row-DFT output [h][kw], 16384 B
  __shared__ float ls1[4], ls2[4];

  const int t = threadIdx.x;
  const int blk = blockIdx.x;

  if (blk < PT_BLOCKS) {
    // ---------------- pointwise CRPS path ----------------
    if (blk == 0 && t == 0) *ctr = 0;   // arm kernel-2's last-block counter
    int i4 = (blk * 256 + t) * 4;
    int b = i4 / (NC * NG);
    int cg = i4 - b * (NC * NG);
    const float* base = pred + (size_t)b * (NM * NC * NG) + cg;
    float4 tv = *(const float4*)&tgt[i4];
    float4 p[NM];
#pragma unroll
    for (int m = 0; m < NM; ++m)
      p[m] = *(const float4*)&base[(size_t)m * (NC * NG)];

    float s1 = 0.f, s2 = 0.f;
#pragma unroll
    for (int m = 0; m < NM; ++m)
      s1 += fabsf(p[m].x - tv.x) + fabsf(p[m].y - tv.y) +
            fabsf(p[m].z - tv.z) + fabsf(p[m].w - tv.w);
#pragma unroll
    for (int m = 0; m < NM; ++m)
#pragma unroll
      for (int j = m + 1; j < NM; ++j)
        s2 += fabsf(p[m].x - p[j].x) + fabsf(p[m].y - p[j].y) +
              fabsf(p[m].z - p[j].z) + fabsf(p[m].w - p[j].w);

    for (int off = 32; off > 0; off >>= 1) {
      s1 += __shfl_down(s1, off);
      s2 += __shfl_down(s2, off);
    }
    if ((t & 63) == 0) { ls1[t >> 6] = s1; ls2[t >> 6] = s2; }
    __syncthreads();
    if (t == 0) {
      double a = 0.0, c = 0.0;
#pragma unroll
      for (int w = 0; w < 4; ++w) { a += (double)ls1[w]; c += (double)ls2[w]; }
      pp[blk] = make_double2(a, c);
    }
    return;
  }

  // ---------------- per-image DFT path ----------------
  const int img = blk - PT_BLOCKS;
  const float* src = (img < N_PRED_IMG)
                         ? pred + (size_t)img * NG
                         : tgt + (size_t)(img - N_PRED_IMG) * NG;
  const float4* src4 = (const float4*)src;

  // Row stage: thread -> (kw = t&15, rg = t>>4); owns rows rg+16j, j=0..7.
  const int kw = t & 15, rg = t >> 4;
  float sw, cw;
  sincosf(-2.0f * PI_F * (float)kw / 128.0f, &sw, &cw);
  const float2 stepw = make_float2(cw, sw);   // e^{-2pi i kw/128}

  float ax[8], ay[8];
#pragma unroll
  for (int j = 0; j < 8; ++j) { ax[j] = 0.f; ay[j] = 0.f; }
  const float4* rp[8];
#pragma unroll
  for (int j = 0; j < 8; ++j) rp[j] = src4 + (size_t)(rg + 16 * j) * 32;

  float2 rt = make_float2(1.f, 0.f);           // e^{-2pi i kw*w/128}, w=0
#pragma unroll 2
  for (int w4 = 0; w4 < 32; ++w4) {
    float4 v[8];
#pragma unroll
    for (int j = 0; j < 8; ++j) v[j] = rp[j][w4];
#pragma unroll
    for (int j = 0; j < 8; ++j) {
      ax[j] = fmaf(v[j].x, rt.x, ax[j]); ay[j] = fmaf(v[j].x, rt.y, ay[j]);
    }
    rt = cmul(rt, stepw);
#pragma unroll
    for (int j = 0; j < 8; ++j) {
      ax[j] = fmaf(v[j].y, rt.x, ax[j]); ay[j] = fmaf(v[j].y, rt.y, ay[j]);
    }
    rt = cmul(rt, stepw);
#pragma unroll
    for (int j = 0; j < 8; ++j) {
      ax[j] = fmaf(v[j].z, rt.x, ax[j]); ay[j] = fmaf(v[j].z, rt.y, ay[j]);
    }
    rt = cmul(rt, stepw);
#pragma unroll
    for (int j = 0; j < 8; ++j) {
      ax[j] = fmaf(v[j].w, rt.x, ax[j]); ay[j] = fmaf(v[j].w, rt.y, ay[j]);
    }
    rt = cmul(rt, stepw);
  }
#pragma unroll
  for (int j = 0; j < 8; ++j)
    Yl[(rg + 16 * j) * NKW + kw] = make_float2(ax[j], ay[j]);
  __syncthreads();   // Yl complete

  // Column stage: thread -> (kh = t>>3, kw pair {2j, 2j+1}, j = t&7).
  // One float4 LDS read per h yields both complex Y values.
  const int kh = t >> 3, kw2 = (t & 7) * 2;
  float sh, ch;
  sincosf(-2.0f * PI_F * (float)kh / 128.0f, &sh, &ch);
  const float2 steph = make_float2(ch, sh);
  float axA = 0.f, ayA = 0.f, axB = 0.f, ayB = 0.f;
  float2 rtc = make_float2(1.f, 0.f);          // e^{-2pi i kh*h/128}, h=0
#pragma unroll 8
  for (int h = 0; h < NH; ++h) {
    float4 y2 = *(const float4*)&Yl[h * NKW + kw2];
    axA = fmaf(y2.x, rtc.x, fmaf(-y2.y, rtc.y, axA));
    ayA = fmaf(y2.x, rtc.y, fmaf(y2.y, rtc.x, ayA));
    axB = fmaf(y2.z, rtc.x, fmaf(-y2.w, rtc.y, axB));
    ayB = fmaf(y2.z, rtc.y, fmaf(y2.w, rtc.x, ayB));
    rtc = cmul(rtc, steph);
  }
  float* mo = mag + (size_t)img * NK;
  mo[kh * NKW + kw2] = sqrtf(axA * axA + ayA * ayA);
  mo[kh * NKW + kw2 + 1] = sqrtf(axB * axB + ayB * ayB);
}

// ---------------------------------------------------------------------------
// Kernel 2: frequency CRPS partials + last-block finalize.
__global__ __launch_bounds__(256) void crps_freq_final_kernel(
    const float* __restrict__ mag,    // (408, 512): 384 pred then 24 tgt
    const double2* __restrict__ pp,   // [PT_BLOCKS]
    double2* __restrict__ fp,         // [FQ_BLOCKS]
    unsigned* __restrict__ ctr,
    float* __restrict__ out) {
  const int tid = threadIdx.x;
  int i = blockIdx.x * 256 + tid;
  int b = i / (NC * NK);
  int rem = i - b * (NC * NK);
  const float* pb = mag + (size_t)b * (NM * NC * NK) + rem;
  float t = mag[(size_t)N_PRED_IMG * NK + (size_t)b * (NC * NK) + rem];
  float p[NM];
#pragma unroll
  for (int m = 0; m < NM; ++m) p[m] = pb[(size_t)m * (NC * NK)];
  float s1 = 0.f, s2 = 0.f;
#pragma unroll
  for (int m = 0; m < NM; ++m) s1 += fabsf(p[m] - t);
#pragma unroll
  for (int m = 0; m < NM; ++m)
#pragma unroll
    for (int j = m + 1; j < NM; ++j) s2 += fabsf(p[m] - p[j]);
  for (int off = 32; off > 0; off >>= 1) {
    s1 += __shfl_down(s1, off);
    s2 += __shfl_down(s2, off);
  }
  __shared__ float ls1[4], ls2[4];
  __shared__ int sLast;
  if ((tid & 63) == 0) { ls1[tid >> 6] = s1; ls2[tid >> 6] = s2; }
  __syncthreads();
  if (tid == 0) {
    double a = 0.0, c = 0.0;
#pragma unroll
    for (int w = 0; w < 4; ++w) { a += (double)ls1[w]; c += (double)ls2[w]; }
    fp[blockIdx.x] = make_double2(a, c);
    __threadfence();                      // release fp before counter bump
    unsigned old = atomicAdd(ctr, 1u);
    sLast = (old == FQ_BLOCKS - 1);
  }
  __syncthreads();
  if (!sLast) return;
  __threadfence();                        // acquire other blocks' fp

  // ---- final reduction (one block) ----
  double s1p = 0.0, s2p = 0.0, s1f = 0.0, s2f = 0.0;
  for (int j = tid; j < PT_BLOCKS; j += 256) {
    double2 v = pp[j]; s1p += v.x; s2p += v.y;
  }
  if (tid < FQ_BLOCKS) { double2 v = fp[tid]; s1f += v.x; s2f += v.y; }
  for (int off = 32; off > 0; off >>= 1) {
    s1p += __shfl_down(s1p, off);
    s2p += __shfl_down(s2p, off);
    s1f += __shfl_down(s1f, off);
    s2f += __shfl_down(s2f, off);
  }
  __shared__ double l[4][4];
  if ((tid & 63) == 0) {
    int w = tid >> 6;
    l[w][0] = s1p; l[w][1] = s2p; l[w][2] = s1f; l[w][3] = s2f;
  }
  __syncthreads();
  if (tid == 0) {
    double a0 = 0, a1 = 0, a2 = 0, a3 = 0;
#pragma unroll
    for (int w = 0; w < 4; ++w) {
      a0 += l[w][0]; a1 += l[w][1]; a2 += l[w][2]; a3 += l[w][3];
    }
    const double Bd = NB, Md = NM, Cd = NC, Gd = NG, Gfd = NGF;
    const double eps = 0.05 / Md;
    double term1_p = a0 / (Bd * Cd * Gd * Md);
    double term2_p = (1.0 - eps) * 2.0 * a1 / ((Md - 1.0) * Bd * Md * Cd * Gd);
    double crps_p = term1_p - 0.5 * term2_p;
    double term1_f = a2 / (Bd * Cd * Gfd * Md);
    double term2_f = (1.0 - eps) * 2.0 * a3 / ((Md - 1.0) * Bd * Md * Cd * Gfd);
    double crps_f = term1_f - 0.5 * term2_f;
    out[0] = (float)(crps_p + 0.1 * crps_f);
  }
}

// ---------------------------------------------------------------------------
extern "C" void kernel_launch(void* const* d_in, const int* in_sizes, int n_in,
                              void* d_out, int out_size, void* d_ws, size_t ws_size,
                              hipStream_t stream) {
  (void)in_sizes; (void)n_in; (void)out_size; (void)ws_size;
  const float* tgt = (const float*)d_in[0];   // (8,3,128,128)
  const float* pred = (const float*)d_in[1];  // (8,16,3,128,128)
  float* out = (float*)d_out;

  char* ws = (char*)d_ws;
  double2* pp = (double2*)(ws + WS_PP_OFF);
  double2* fp = (double2*)(ws + WS_FP_OFF);
  unsigned* ctr = (unsigned*)(ws + WS_CTR_OFF);
  float* mag = (float*)(ws + WS_MAG_OFF);

  fused_main_kernel<<<PT_BLOCKS + N_IMG, 256, 0, stream>>>(pred, tgt, pp, mag, ctr);
  crps_freq_final_kernel<<<FQ_BLOCKS, 256, 0, stream>>>(mag, pp, fp, ctr, out);
}